// Round 1
// baseline (645.655 us; speedup 1.0000x reference)
//
#include <hip/hip_runtime.h>
#include <hip/hip_bf16.h>
#include <stdint.h>

#define N_TOK 4096
#define DDIM  1024
#define HDIM  768
#define NEXP  23
#define TOPK  3

typedef float  floatx4 __attribute__((ext_vector_type(4)));
typedef short  short8  __attribute__((ext_vector_type(8)));

__device__ __forceinline__ short f2bf(float f) {
    __hip_bfloat16 h = __float2bfloat16(f);
    return *reinterpret_cast<short*>(&h);
}

__device__ __forceinline__ float gelu_erf(float v) {
    return 0.5f * v * (1.0f + erff(v * 0.70710678118654752f));
}

// ---------------------------------------------------------------- gate + topk
// one wave per token; fp32 exact gate so top-k matches the fp32 reference
__global__ __launch_bounds__(256) void gate_kernel(
    const float* __restrict__ x, const float* __restrict__ gate_W,
    const float* __restrict__ gate_b, const float* __restrict__ route_bias,
    int* __restrict__ top_idx, float* __restrict__ top_w,
    float* __restrict__ psum_part)
{
    const int wave = threadIdx.x >> 6, lane = threadIdx.x & 63;
    const int n = blockIdx.x * 4 + wave;

    float acc[NEXP];
#pragma unroll
    for (int e = 0; e < NEXP; e++) acc[e] = 0.f;

    const float* xr = x + (size_t)n * DDIM;
    for (int i = 0; i < DDIM / 64; i++) {
        int d = i * 64 + lane;
        float xd = xr[d];
        const float* g = gate_W + (size_t)d * NEXP;
#pragma unroll
        for (int e = 0; e < NEXP; e++) acc[e] += xd * g[e];
    }
    // butterfly reduce across 64 lanes
    for (int off = 32; off > 0; off >>= 1) {
#pragma unroll
        for (int e = 0; e < NEXP; e++) acc[e] += __shfl_xor(acc[e], off, 64);
    }

    float p[NEXP], s = 0.f;
#pragma unroll
    for (int e = 0; e < NEXP; e++) {
        p[e] = 1.f / (1.f + expf(-(acc[e] + gate_b[e])));
        s += p[e];
    }
    const float inv = 1.f / s;

    __shared__ float ps[4][NEXP];
    if (lane == 0) {
#pragma unroll
        for (int e = 0; e < NEXP; e++) ps[wave][e] = p[e] * inv;

        // top-3, strict > picks lowest index on ties (lax.top_k rule)
        int   idx[TOPK];
        float w[TOPK];
        bool  used[NEXP] = {};
        for (int k = 0; k < TOPK; k++) {
            float best = -1e30f; int bi = 0;
            for (int e = 0; e < NEXP; e++) {
                if (!used[e]) {
                    float sc = p[e] + route_bias[e];
                    if (sc > best) { best = sc; bi = e; }
                }
            }
            used[bi] = true; idx[k] = bi; w[k] = p[bi];
        }
        float wsum = w[0] + w[1] + w[2];
        for (int k = 0; k < TOPK; k++) {
            top_idx[n * TOPK + k] = idx[k];
            top_w[n * TOPK + k]   = w[k] / wsum;
        }
    }
    __syncthreads();
    if (threadIdx.x < NEXP) {
        int e = threadIdx.x;
        psum_part[(size_t)blockIdx.x * NEXP + e] =
            ps[0][e] + ps[1][e] + ps[2][e] + ps[3][e];
    }
}

// ---------------------------------------------------- counts/offsets/aux loss
__global__ __launch_bounds__(256) void aux_kernel(
    const int* __restrict__ top_idx, const float* __restrict__ psum_part,
    int* __restrict__ offsets, int* __restrict__ cursor,
    float* __restrict__ out_aux)
{
    __shared__ int   cnt[NEXP];
    __shared__ float psum[NEXP];
    const int t = threadIdx.x;
    if (t < NEXP) { cnt[t] = 0; psum[t] = 0.f; }
    __syncthreads();

    for (int i = t; i < N_TOK * TOPK; i += 256)
        atomicAdd(&cnt[top_idx[i]], 1);

    float loc[NEXP];
#pragma unroll
    for (int e = 0; e < NEXP; e++) loc[e] = 0.f;
    for (int b = t; b < N_TOK / 4; b += 256) {
        const float* row = psum_part + (size_t)b * NEXP;
#pragma unroll
        for (int e = 0; e < NEXP; e++) loc[e] += row[e];
    }
#pragma unroll
    for (int e = 0; e < NEXP; e++) atomicAdd(&psum[e], loc[e]);
    __syncthreads();

    if (t == 0) {
        int off = 0; float aux = 0.f;
        for (int e = 0; e < NEXP; e++) {
            offsets[e] = off; cursor[e] = 0;
            float P = psum[e] / (float)N_TOK;
            float F = (float)NEXP * (float)cnt[e] / ((float)TOPK * (float)N_TOK);
            aux += P * F;
            off += cnt[e];
        }
        offsets[NEXP] = off;
        *out_aux = aux;
    }
}

// ----------------------------------------------------------- scatter to groups
__global__ __launch_bounds__(256) void scatter_kernel(
    const int* __restrict__ top_idx, const float* __restrict__ top_w,
    const int* __restrict__ offsets, int* __restrict__ cursor,
    int* __restrict__ tok_of_slot, float* __restrict__ w_of_slot)
{
    int n = blockIdx.x * 256 + threadIdx.x;
    if (n >= N_TOK) return;
    for (int k = 0; k < TOPK; k++) {
        int e = top_idx[n * TOPK + k];
        int pos = atomicAdd(&cursor[e], 1);
        int slot = offsets[e] + pos;
        tok_of_slot[slot] = n;
        w_of_slot[slot]   = top_w[n * TOPK + k];
    }
}

// --------------------------------------------------------------- FFN1 (x->h)
// C[m][n] = gelu( X[tok m] @ W[:, n] + b1[n] ), stored bf16.
// MFMA 16x16x32 bf16; A frag: A[m=lane&15][k=quad*8+j]; B staged transposed.
template <bool GATHER>
__global__ __launch_bounds__(256) void ffn1_kernel(
    const float* __restrict__ x, const float* __restrict__ W1,
    const float* __restrict__ b1, const int* __restrict__ offsets,
    const int* __restrict__ tok_of_slot, short* __restrict__ hbuf)
{
    int e = 0, slot0 = 0, M = N_TOK;
    if constexpr (GATHER) {
        e = blockIdx.z;
        slot0 = offsets[e];
        M = offsets[e + 1] - slot0;
    }
    const int m0 = blockIdx.y * 64;
    if (m0 >= M) return;
    const int n0 = blockIdx.x * 64;
    const float* W = W1 + (size_t)e * DDIM * HDIM;

    __shared__ short As[64][40];   // +8 pad keeps 16B align & kills conflicts
    __shared__ short BsT[64][40];  // B transposed: BsT[n][k]

    const int t = threadIdx.x;
    const int wave = t >> 6, lane = t & 63;
    const int quad = lane >> 4, l16 = lane & 15;

    const int am = t >> 2;          // 0..63 row
    const int ak = (t & 3) << 3;    // 0,8,16,24
    const int gm = m0 + am;
    const bool avalid = (gm < M);
    const float* arow = nullptr;
    if (avalid) {
        int tok;
        if constexpr (GATHER) tok = tok_of_slot[slot0 + gm];
        else                  tok = gm;
        arow = x + (size_t)tok * DDIM;
    }
    const int bk = t >> 3;          // 0..31
    const int bn = (t & 7) << 3;    // 0..56

    floatx4 acc[4] = {};

    for (int k0 = 0; k0 < DDIM; k0 += 32) {
        if (avalid) {
            float4 v0 = *(const float4*)(arow + k0 + ak);
            float4 v1 = *(const float4*)(arow + k0 + ak + 4);
            short* dst = &As[am][ak];
            dst[0] = f2bf(v0.x); dst[1] = f2bf(v0.y);
            dst[2] = f2bf(v0.z); dst[3] = f2bf(v0.w);
            dst[4] = f2bf(v1.x); dst[5] = f2bf(v1.y);
            dst[6] = f2bf(v1.z); dst[7] = f2bf(v1.w);
        } else {
            short* dst = &As[am][ak];
#pragma unroll
            for (int i = 0; i < 8; i++) dst[i] = 0;
        }
        const float* brow = W + (size_t)(k0 + bk) * HDIM + n0 + bn;
        float4 w0 = *(const float4*)(brow);
        float4 w1 = *(const float4*)(brow + 4);
        BsT[bn + 0][bk] = f2bf(w0.x); BsT[bn + 1][bk] = f2bf(w0.y);
        BsT[bn + 2][bk] = f2bf(w0.z); BsT[bn + 3][bk] = f2bf(w0.w);
        BsT[bn + 4][bk] = f2bf(w1.x); BsT[bn + 5][bk] = f2bf(w1.y);
        BsT[bn + 6][bk] = f2bf(w1.z); BsT[bn + 7][bk] = f2bf(w1.w);
        __syncthreads();

        short8 a = *(const short8*)&As[wave * 16 + l16][quad * 8];
#pragma unroll
        for (int nt = 0; nt < 4; nt++) {
            short8 b = *(const short8*)&BsT[nt * 16 + l16][quad * 8];
            acc[nt] = __builtin_amdgcn_mfma_f32_16x16x32_bf16(a, b, acc[nt], 0, 0, 0);
        }
        __syncthreads();
    }

#pragma unroll
    for (int nt = 0; nt < 4; nt++) {
        int col = n0 + nt * 16 + l16;
        float bias = b1[(GATHER ? e * HDIM : 0) + col];
#pragma unroll
        for (int r = 0; r < 4; r++) {
            int mrow = wave * 16 + quad * 4 + r;   // C/D: row=quad*4+reg, col=lane&15
            if (m0 + mrow < M) {
                float v = acc[nt][r] + bias;
                hbuf[(size_t)(slot0 + m0 + mrow) * HDIM + col] = f2bf(gelu_erf(v));
            }
        }
    }
}

// --------------------------------------------------------------- FFN2 (h->y)
template <bool GATHER>
__global__ __launch_bounds__(256) void ffn2_kernel(
    const short* __restrict__ hbuf, const float* __restrict__ W2,
    const float* __restrict__ b2, const int* __restrict__ offsets,
    const int* __restrict__ tok_of_slot, const float* __restrict__ w_of_slot,
    float* __restrict__ out)
{
    int e = 0, slot0 = 0, M = N_TOK;
    if constexpr (GATHER) {
        e = blockIdx.z;
        slot0 = offsets[e];
        M = offsets[e + 1] - slot0;
    }
    const int m0 = blockIdx.y * 64;
    if (m0 >= M) return;
    const int n0 = blockIdx.x * 64;
    const float* W = W2 + (size_t)e * HDIM * DDIM;

    __shared__ short As[64][40];
    __shared__ short BsT[64][40];

    const int t = threadIdx.x;
    const int wave = t >> 6, lane = t & 63;
    const int quad = lane >> 4, l16 = lane & 15;

    const int am = t >> 2;
    const int ak = (t & 3) << 3;
    const int gm = m0 + am;
    const bool avalid = (gm < M);
    const short* hrow = hbuf + (size_t)(slot0 + gm) * HDIM;

    const int bk = t >> 3;
    const int bn = (t & 7) << 3;

    floatx4 acc[4] = {};

    for (int k0 = 0; k0 < HDIM; k0 += 32) {
        if (avalid) {
            *(short8*)&As[am][ak] = *(const short8*)(hrow + k0 + ak);
        } else {
            short* dst = &As[am][ak];
#pragma unroll
            for (int i = 0; i < 8; i++) dst[i] = 0;
        }
        const float* brow = W + (size_t)(k0 + bk) * DDIM + n0 + bn;
        float4 w0 = *(const float4*)(brow);
        float4 w1 = *(const float4*)(brow + 4);
        BsT[bn + 0][bk] = f2bf(w0.x); BsT[bn + 1][bk] = f2bf(w0.y);
        BsT[bn + 2][bk] = f2bf(w0.z); BsT[bn + 3][bk] = f2bf(w0.w);
        BsT[bn + 4][bk] = f2bf(w1.x); BsT[bn + 5][bk] = f2bf(w1.y);
        BsT[bn + 6][bk] = f2bf(w1.z); BsT[bn + 7][bk] = f2bf(w1.w);
        __syncthreads();

        short8 a = *(const short8*)&As[wave * 16 + l16][quad * 8];
#pragma unroll
        for (int nt = 0; nt < 4; nt++) {
            short8 b = *(const short8*)&BsT[nt * 16 + l16][quad * 8];
            acc[nt] = __builtin_amdgcn_mfma_f32_16x16x32_bf16(a, b, acc[nt], 0, 0, 0);
        }
        __syncthreads();
    }

#pragma unroll
    for (int nt = 0; nt < 4; nt++) {
        int col = n0 + nt * 16 + l16;
        float bias = b2[(GATHER ? e * DDIM : 0) + col];
#pragma unroll
        for (int r = 0; r < 4; r++) {
            int mrow = wave * 16 + quad * 4 + r;
            int lm = m0 + mrow;
            if (lm < M) {
                float v = acc[nt][r] + bias;
                if constexpr (GATHER) {
                    int slot = slot0 + lm;
                    int tok = tok_of_slot[slot];
                    float w = w_of_slot[slot];
                    atomicAdd(&out[(size_t)tok * DDIM + col], w * v);
                } else {
                    out[(size_t)lm * DDIM + col] = v;
                }
            }
        }
    }
}

// ---------------------------------------------------------------------- launch
extern "C" void kernel_launch(void* const* d_in, const int* in_sizes, int n_in,
                              void* d_out, int out_size, void* d_ws, size_t ws_size,
                              hipStream_t stream)
{
    const float* x          = (const float*)d_in[0];
    const float* gate_W     = (const float*)d_in[1];
    const float* gate_b     = (const float*)d_in[2];
    const float* route_bias = (const float*)d_in[3];
    const float* W1         = (const float*)d_in[4];
    const float* b1         = (const float*)d_in[5];
    const float* W2         = (const float*)d_in[6];
    const float* b2         = (const float*)d_in[7];
    const float* sW1        = (const float*)d_in[8];
    const float* sb1        = (const float*)d_in[9];
    const float* sW2        = (const float*)d_in[10];
    const float* sb2        = (const float*)d_in[11];
    float* out = (float*)d_out;

    uint8_t* ws = (uint8_t*)d_ws;
    int*   top_idx   = (int*)(ws);                    // 49152 B
    float* top_w     = (float*)(ws + 49152);          // 49152 B
    int*   offsets   = (int*)(ws + 98304);            // 96 B (pad 256)
    int*   cursor    = (int*)(ws + 98560);            // 92 B (pad 256)
    float* psum_part = (float*)(ws + 98816);          // 1024*23*4 = 94208 B
    int*   tok_slot  = (int*)(ws + 193024);           // 49152 B
    float* w_slot    = (float*)(ws + 242176);         // 49152 B
    short* hbuf      = (short*)(ws + 291328);         // 12288*768*2 = 18874368 B
    short* hsbuf     = (short*)(ws + 19165696);       // 4096*768*2  = 6291456 B
    // total ~25.5 MB

    gate_kernel<<<N_TOK / 4, 256, 0, stream>>>(x, gate_W, gate_b, route_bias,
                                               top_idx, top_w, psum_part);
    aux_kernel<<<1, 256, 0, stream>>>(top_idx, psum_part, offsets, cursor,
                                      out + (size_t)N_TOK * DDIM);
    scatter_kernel<<<N_TOK / 256, 256, 0, stream>>>(top_idx, top_w, offsets, cursor,
                                                    tok_slot, w_slot);
    // shared MLP writes out first (plain stores), routed experts atomicAdd after
    ffn1_kernel<false><<<dim3(HDIM / 64, N_TOK / 64, 1), 256, 0, stream>>>(
        x, sW1, sb1, nullptr, nullptr, hsbuf);
    ffn2_kernel<false><<<dim3(DDIM / 64, N_TOK / 64, 1), 256, 0, stream>>>(
        hsbuf, sW2, sb2, nullptr, nullptr, nullptr, out);
    ffn1_kernel<true><<<dim3(HDIM / 64, N_TOK / 64, NEXP), 256, 0, stream>>>(
        x, W1, b1, offsets, tok_slot, hbuf);
    ffn2_kernel<true><<<dim3(DDIM / 64, N_TOK / 64, NEXP), 256, 0, stream>>>(
        hbuf, W2, b2, offsets, tok_slot, w_slot, out);
}

// Round 2
// 586.427 us; speedup vs baseline: 1.1010x; 1.1010x over previous
//
#include <hip/hip_runtime.h>
#include <hip/hip_bf16.h>
#include <stdint.h>

#define N_TOK 4096
#define DDIM  1024
#define HDIM  768
#define NEXP  23
#define TOPK  3

typedef float floatx4 __attribute__((ext_vector_type(4)));
typedef short short8  __attribute__((ext_vector_type(8)));

__device__ __forceinline__ short f2bf(float f) {
    __hip_bfloat16 h = __float2bfloat16(f);
    return *reinterpret_cast<short*>(&h);
}
__device__ __forceinline__ float gelu_erf(float v) {
    return 0.5f * v * (1.0f + erff(v * 0.70710678118654752f));
}
// async global->LDS, 16B per lane; lds dest must be wave-uniform base (lane*16 added by HW)
__device__ __forceinline__ void gl_lds16(const short* g, short* l) {
    __builtin_amdgcn_global_load_lds(
        (const __attribute__((address_space(1))) void*)g,
        (__attribute__((address_space(3))) void*)l, 16, 0, 0);
}

// ---------------------------------------------------------------- gate + topk
// one wave per token; fp32 exact gate so top-k matches the fp32 reference.
// gate_W staged through LDS in 64-row chunks (coalesced).
__global__ __launch_bounds__(256) void gate_kernel(
    const float* __restrict__ x, const float* __restrict__ gate_W,
    const float* __restrict__ gate_b, const float* __restrict__ route_bias,
    int* __restrict__ top_idx, float* __restrict__ top_w,
    float* __restrict__ psum_part)
{
    const int wave = threadIdx.x >> 6, lane = threadIdx.x & 63;
    const int n = blockIdx.x * 4 + wave;

    __shared__ float gw[64][25];   // 25 stride: bank-conflict-free column reads
    float acc[NEXP];
#pragma unroll
    for (int e = 0; e < NEXP; e++) acc[e] = 0.f;

    const float* xr = x + (size_t)n * DDIM;
    for (int c0 = 0; c0 < DDIM; c0 += 64) {
        for (int idx = threadIdx.x; idx < 64 * NEXP; idx += 256)
            gw[idx / NEXP][idx % NEXP] = gate_W[(size_t)c0 * NEXP + idx];
        __syncthreads();
        float xd = xr[c0 + lane];
#pragma unroll
        for (int e = 0; e < NEXP; e++) acc[e] += xd * gw[lane][e];
        __syncthreads();
    }
    for (int off = 32; off > 0; off >>= 1) {
#pragma unroll
        for (int e = 0; e < NEXP; e++) acc[e] += __shfl_xor(acc[e], off, 64);
    }

    float p[NEXP], s = 0.f;
#pragma unroll
    for (int e = 0; e < NEXP; e++) {
        p[e] = 1.f / (1.f + expf(-(acc[e] + gate_b[e])));
        s += p[e];
    }
    const float inv = 1.f / s;

    __shared__ float ps[4][NEXP];
    if (lane == 0) {
#pragma unroll
        for (int e = 0; e < NEXP; e++) ps[wave][e] = p[e] * inv;
        // top-3, strict > picks lowest index on ties (lax.top_k rule)
        int idx[TOPK]; float w[TOPK]; bool used[NEXP] = {};
        for (int k = 0; k < TOPK; k++) {
            float best = -1e30f; int bi = 0;
            for (int e = 0; e < NEXP; e++) {
                if (!used[e]) {
                    float sc = p[e] + route_bias[e];
                    if (sc > best) { best = sc; bi = e; }
                }
            }
            used[bi] = true; idx[k] = bi; w[k] = p[bi];
        }
        float wsum = w[0] + w[1] + w[2];
        for (int k = 0; k < TOPK; k++) {
            top_idx[n * TOPK + k] = idx[k];
            top_w[n * TOPK + k]   = w[k] / wsum;
        }
    }
    __syncthreads();
    if (threadIdx.x < NEXP) {
        int e = threadIdx.x;
        psum_part[(size_t)blockIdx.x * NEXP + e] =
            ps[0][e] + ps[1][e] + ps[2][e] + ps[3][e];
    }
}

// ---------------------------------------------------- counts/offsets/aux loss
__global__ __launch_bounds__(256) void aux_kernel(
    const int* __restrict__ top_idx, const float* __restrict__ psum_part,
    int* __restrict__ offsets, int* __restrict__ cursor,
    float* __restrict__ out_aux)
{
    __shared__ int   cnt[NEXP];
    __shared__ float psum[NEXP];
    const int t = threadIdx.x;
    if (t < NEXP) { cnt[t] = 0; psum[t] = 0.f; }
    __syncthreads();

    for (int i = t; i < N_TOK * TOPK; i += 256)
        atomicAdd(&cnt[top_idx[i]], 1);

    float loc[NEXP];
#pragma unroll
    for (int e = 0; e < NEXP; e++) loc[e] = 0.f;
    for (int b = t; b < N_TOK / 4; b += 256) {
        const float* row = psum_part + (size_t)b * NEXP;
#pragma unroll
        for (int e = 0; e < NEXP; e++) loc[e] += row[e];
    }
#pragma unroll
    for (int e = 0; e < NEXP; e++) atomicAdd(&psum[e], loc[e]);
    __syncthreads();

    if (t == 0) {
        int off = 0; float aux = 0.f;
        for (int e = 0; e < NEXP; e++) {
            offsets[e] = off; cursor[e] = 0;
            float P = psum[e] / (float)N_TOK;
            float F = (float)NEXP * (float)cnt[e] / ((float)TOPK * (float)N_TOK);
            aux += P * F;
            off += cnt[e];
        }
        offsets[NEXP] = off;
        *out_aux = aux;
    }
}

// ----------------------------------------------------------- scatter to groups
__global__ __launch_bounds__(256) void scatter_kernel(
    const int* __restrict__ top_idx, const float* __restrict__ top_w,
    const int* __restrict__ offsets, int* __restrict__ cursor,
    int* __restrict__ tok_of_slot, float* __restrict__ w_of_slot)
{
    int n = blockIdx.x * 256 + threadIdx.x;
    if (n >= N_TOK) return;
    for (int k = 0; k < TOPK; k++) {
        int e = top_idx[n * TOPK + k];
        int pos = atomicAdd(&cursor[e], 1);
        int slot = offsets[e] + pos;
        tok_of_slot[slot] = n;
        w_of_slot[slot]   = top_w[n * TOPK + k];
    }
}

// -------------------------------------------------------- x fp32 -> bf16 (+zero row)
__global__ __launch_bounds__(256) void xcvt_kernel(
    const float* __restrict__ x, short* __restrict__ xb)
{
    size_t i = (size_t)blockIdx.x * 256 + threadIdx.x;   // one float4 each
    float4 v = ((const float4*)x)[i];
    short4 o;
    o.x = f2bf(v.x); o.y = f2bf(v.y); o.z = f2bf(v.z); o.w = f2bf(v.w);
    ((short4*)xb)[i] = o;
    if (blockIdx.x == 0) {
        short4 z; z.x = 0; z.y = 0; z.z = 0; z.w = 0;
        ((short4*)(xb + (size_t)N_TOK * DDIM))[threadIdx.x] = z;  // zero row
    }
}

// ------------------------------------ transpose+convert: src[R][C] f32 -> dst[C][R] bf16
__global__ __launch_bounds__(256) void tcvt_kernel(
    const float* __restrict__ src, short* __restrict__ dst, int R, int C)
{
    __shared__ short tile[64][66];   // stored [c][r]; stride 66 => conflict-free
    const float* s = src + (size_t)blockIdx.z * R * C;
    short* d = dst + (size_t)blockIdx.z * R * C;
    const int c0 = blockIdx.x * 64, r0 = blockIdx.y * 64;
    const int tc = threadIdx.x & 63, tq = threadIdx.x >> 6;

    for (int i = 0; i < 64; i += 4) {
        int r = i + tq;
        tile[tc][r] = f2bf(s[(size_t)(r0 + r) * C + c0 + tc]);
    }
    __syncthreads();
    for (int j = 0; j < 64; j += 4) {
        int c = j + tq;
        d[(size_t)(c0 + c) * R + r0 + tc] = tile[c][tc];
    }
}

// --------------------------------------------------------------- unified GEMM
// C = A(bf16 rows) @ B^T(bf16, BT[n][k]); 128x128 tile, BK=32, 4 waves, 4x4 frags.
// FFN1: epilogue gelu -> bf16 hout.  !FFN1: bias, plain store (shared) or w*atomicAdd (routed).
template <bool FFN1, bool GATHER>
__global__ __launch_bounds__(256) void gemm_kernel(
    const short* __restrict__ Abase, const short* __restrict__ BT,
    const float* __restrict__ bias, const int* __restrict__ offsets,
    const int* __restrict__ tok_of_slot, const float* __restrict__ w_of_slot,
    const short* __restrict__ zrow,
    short* __restrict__ hout, float* __restrict__ out)
{
    constexpr int KD = FFN1 ? DDIM : HDIM;
    constexpr int NC = FFN1 ? HDIM : DDIM;

    int e = 0, slot0 = 0, M = N_TOK;
    if constexpr (GATHER) {
        e = blockIdx.z;
        slot0 = offsets[e];
        M = offsets[e + 1] - slot0;
    }
    const int m0 = blockIdx.y * 128;
    if (m0 >= M) return;
    const int n0 = blockIdx.x * 128;

    __shared__ short As[128 * 32];
    __shared__ short Bs[128 * 32];

    const int t = threadIdx.x;
    const int w = t >> 6, l = t & 63;
    const int quad = l >> 4, l16 = l & 15;
    const int wr = w >> 1, wc = w & 1;

    // staging: thread covers rows ra0 & ra1, 16B at column (l&3)*8
    const int ra0 = w * 32 + (l >> 2);
    const int ra1 = ra0 + 16;
    const int ko  = (l & 3) << 3;

    const short *ap0, *ap1;
    {
        const int r0i = m0 + ra0, r1i = m0 + ra1;
        if constexpr (GATHER) {
            if constexpr (FFN1) {
                ap0 = (r0i < M) ? Abase + (size_t)tok_of_slot[slot0 + r0i] * KD : zrow;
                ap1 = (r1i < M) ? Abase + (size_t)tok_of_slot[slot0 + r1i] * KD : zrow;
            } else {
                ap0 = (r0i < M) ? Abase + (size_t)(slot0 + r0i) * KD : zrow;
                ap1 = (r1i < M) ? Abase + (size_t)(slot0 + r1i) * KD : zrow;
            }
        } else {
            ap0 = Abase + (size_t)r0i * KD;
            ap1 = Abase + (size_t)r1i * KD;
        }
    }
    ap0 += ko; ap1 += ko;
    const short* bbase = BT + (size_t)e * NC * KD + (size_t)n0 * KD;
    const short* bp0 = bbase + (size_t)ra0 * KD + ko;
    const short* bp1 = bbase + (size_t)ra1 * KD + ko;

    short* asd0 = As + (w * 32) * 32;
    short* asd1 = As + (w * 32 + 16) * 32;
    short* bsd0 = Bs + (w * 32) * 32;
    short* bsd1 = Bs + (w * 32 + 16) * 32;

    floatx4 acc[4][4] = {};

    for (int k0 = 0; k0 < KD; k0 += 32) {
        gl_lds16(ap0, asd0); gl_lds16(ap1, asd1);
        gl_lds16(bp0, bsd0); gl_lds16(bp1, bsd1);
        ap0 += 32; ap1 += 32; bp0 += 32; bp1 += 32;
        __syncthreads();

        short8 af[4], bf[4];
#pragma unroll
        for (int i = 0; i < 4; i++)
            af[i] = *(const short8*)&As[(wr * 64 + i * 16 + l16) * 32 + quad * 8];
#pragma unroll
        for (int j = 0; j < 4; j++)
            bf[j] = *(const short8*)&Bs[(wc * 64 + j * 16 + l16) * 32 + quad * 8];
#pragma unroll
        for (int i = 0; i < 4; i++)
#pragma unroll
            for (int j = 0; j < 4; j++)
                acc[i][j] = __builtin_amdgcn_mfma_f32_16x16x32_bf16(af[i], bf[j], acc[i][j], 0, 0, 0);
        __syncthreads();
    }

    const int bias_off = e * NC;
    if constexpr (FFN1) {
#pragma unroll
        for (int j = 0; j < 4; j++) {
            const int col = n0 + wc * 64 + j * 16 + l16;
            const float bv = bias[bias_off + col];
#pragma unroll
            for (int i = 0; i < 4; i++)
#pragma unroll
                for (int r = 0; r < 4; r++) {
                    const int row = m0 + wr * 64 + i * 16 + quad * 4 + r;
                    if (row < M) {
                        const size_t orow = GATHER ? (size_t)(slot0 + row) : (size_t)row;
                        hout[orow * NC + col] = f2bf(gelu_erf(acc[i][j][r] + bv));
                    }
                }
        }
    } else {
        int   toks[4][4];
        float wgt[4][4];
        if constexpr (GATHER) {
#pragma unroll
            for (int i = 0; i < 4; i++)
#pragma unroll
                for (int r = 0; r < 4; r++) {
                    const int row = m0 + wr * 64 + i * 16 + quad * 4 + r;
                    if (row < M) {
                        toks[i][r] = tok_of_slot[slot0 + row];
                        wgt[i][r]  = w_of_slot[slot0 + row];
                    } else toks[i][r] = -1;
                }
        }
#pragma unroll
        for (int j = 0; j < 4; j++) {
            const int col = n0 + wc * 64 + j * 16 + l16;
            const float bv = bias[bias_off + col];
#pragma unroll
            for (int i = 0; i < 4; i++)
#pragma unroll
                for (int r = 0; r < 4; r++) {
                    const float v = acc[i][j][r] + bv;
                    if constexpr (GATHER) {
                        if (toks[i][r] >= 0)
                            atomicAdd(&out[(size_t)toks[i][r] * NC + col], wgt[i][r] * v);
                    } else {
                        const int row = m0 + wr * 64 + i * 16 + quad * 4 + r;
                        out[(size_t)row * NC + col] = v;
                    }
                }
        }
    }
}

// ---------------------------------------------------------------------- launch
extern "C" void kernel_launch(void* const* d_in, const int* in_sizes, int n_in,
                              void* d_out, int out_size, void* d_ws, size_t ws_size,
                              hipStream_t stream)
{
    const float* x          = (const float*)d_in[0];
    const float* gate_W     = (const float*)d_in[1];
    const float* gate_b     = (const float*)d_in[2];
    const float* route_bias = (const float*)d_in[3];
    const float* W1         = (const float*)d_in[4];
    const float* b1         = (const float*)d_in[5];
    const float* W2         = (const float*)d_in[6];
    const float* b2         = (const float*)d_in[7];
    const float* sW1        = (const float*)d_in[8];
    const float* sb1        = (const float*)d_in[9];
    const float* sW2        = (const float*)d_in[10];
    const float* sb2        = (const float*)d_in[11];
    float* out = (float*)d_out;

    uint8_t* ws = (uint8_t*)d_ws;
    int*   top_idx   = (int*)(ws);                    //     49152
    float* top_w     = (float*)(ws + 49152);          //     49152
    int*   offsets   = (int*)(ws + 98304);            //       256
    int*   cursor    = (int*)(ws + 98560);            //       256
    float* psum_part = (float*)(ws + 98816);          //     94208
    int*   tok_slot  = (int*)(ws + 193024);           //     49152
    float* w_slot    = (float*)(ws + 242176);         //     49152
    short* xb        = (short*)(ws + 291328);         //   8390656  (4097 rows; last = zeros)
    short* hbuf      = (short*)(ws + 8681984);        //  18874368
    short* hsbuf     = (short*)(ws + 27556352);       //   6291456
    short* W1T       = (short*)(ws + 33847808);       //  36175872  [E][H][D]
    short* W2T       = (short*)(ws + 70023680);       //  36175872  [E][D][H]
    short* sW1T      = (short*)(ws + 106199552);      //   1572864  [H][D]
    short* sW2T      = (short*)(ws + 107772416);      //   1572864  [D][H]
    const short* zrow = xb + (size_t)N_TOK * DDIM;    // total ~104.3 MB

    // prep: conversions + routing
    xcvt_kernel<<<N_TOK * DDIM / 4 / 256, 256, 0, stream>>>(x, xb);
    tcvt_kernel<<<dim3(HDIM / 64, DDIM / 64, NEXP), 256, 0, stream>>>(W1, W1T, DDIM, HDIM);
    tcvt_kernel<<<dim3(DDIM / 64, HDIM / 64, NEXP), 256, 0, stream>>>(W2, W2T, HDIM, DDIM);
    tcvt_kernel<<<dim3(HDIM / 64, DDIM / 64, 1), 256, 0, stream>>>(sW1, sW1T, DDIM, HDIM);
    tcvt_kernel<<<dim3(DDIM / 64, HDIM / 64, 1), 256, 0, stream>>>(sW2, sW2T, HDIM, DDIM);
    gate_kernel<<<N_TOK / 4, 256, 0, stream>>>(x, gate_W, gate_b, route_bias,
                                               top_idx, top_w, psum_part);
    aux_kernel<<<1, 256, 0, stream>>>(top_idx, psum_part, offsets, cursor,
                                      out + (size_t)N_TOK * DDIM);
    scatter_kernel<<<N_TOK / 256, 256, 0, stream>>>(top_idx, top_w, offsets, cursor,
                                                    tok_slot, w_slot);

    // shared ffn1 -> routed ffn1 -> shared ffn2 (plain stores) -> routed ffn2 (atomicAdd)
    gemm_kernel<true, false><<<dim3(HDIM / 128, N_TOK / 128, 1), 256, 0, stream>>>(
        xb, sW1T, sb1, nullptr, nullptr, nullptr, zrow, hsbuf, nullptr);
    gemm_kernel<true, true><<<dim3(HDIM / 128, N_TOK / 128, NEXP), 256, 0, stream>>>(
        xb, W1T, b1, offsets, tok_slot, nullptr, zrow, hbuf, nullptr);
    gemm_kernel<false, false><<<dim3(DDIM / 128, N_TOK / 128, 1), 256, 0, stream>>>(
        hsbuf, sW2T, sb2, nullptr, nullptr, nullptr, zrow, nullptr, out);
    gemm_kernel<false, true><<<dim3(DDIM / 128, N_TOK / 128, NEXP), 256, 0, stream>>>(
        hbuf, W2T, b2, offsets, tok_slot, w_slot, zrow, nullptr, out);
}

// Round 3
// 503.053 us; speedup vs baseline: 1.2835x; 1.1657x over previous
//
#include <hip/hip_runtime.h>
#include <hip/hip_bf16.h>
#include <stdint.h>

#define N_TOK 4096
#define DDIM  1024
#define HDIM  768
#define NEXP  23
#define TOPK  3
#define MAXTILE 152            // <=119 routed tiles + 32 shared tiles
#define SLOTS   19456          // padded routed (<=15232) + 4096 shared, rounded up

typedef float floatx4 __attribute__((ext_vector_type(4)));
typedef short short8  __attribute__((ext_vector_type(8)));

__device__ __forceinline__ short f2bf(float f) {
    __hip_bfloat16 h = __float2bfloat16(f);
    return *reinterpret_cast<short*>(&h);
}
__device__ __forceinline__ float bf2f(short s) {
    unsigned u = ((unsigned)(unsigned short)s) << 16;
    return __uint_as_float(u);
}
__device__ __forceinline__ float gelu_erf(float v) {
    return 0.5f * v * (1.0f + erff(v * 0.70710678118654752f));
}
// async global->LDS, 16B/lane; LDS dest wave-uniform base (HW adds lane*16)
__device__ __forceinline__ void gl_lds16(const short* g, short* l) {
    __builtin_amdgcn_global_load_lds(
        (const __attribute__((address_space(1))) void*)g,
        (__attribute__((address_space(3))) void*)l, 16, 0, 0);
}

// ---------------------------------------------------------------- gate + topk
__global__ __launch_bounds__(256) void gate_kernel(
    const float* __restrict__ x, const float* __restrict__ gate_W,
    const float* __restrict__ gate_b, const float* __restrict__ route_bias,
    int* __restrict__ top_idx, float* __restrict__ top_w,
    float* __restrict__ psum_part)
{
    const int wave = threadIdx.x >> 6, lane = threadIdx.x & 63;
    const int n = blockIdx.x * 4 + wave;

    __shared__ float gw[64][25];
    float acc[NEXP];
#pragma unroll
    for (int e = 0; e < NEXP; e++) acc[e] = 0.f;

    const float* xr = x + (size_t)n * DDIM;
    for (int c0 = 0; c0 < DDIM; c0 += 64) {
        for (int idx = threadIdx.x; idx < 64 * NEXP; idx += 256)
            gw[idx / NEXP][idx % NEXP] = gate_W[(size_t)c0 * NEXP + idx];
        __syncthreads();
        float xd = xr[c0 + lane];
#pragma unroll
        for (int e = 0; e < NEXP; e++) acc[e] += xd * gw[lane][e];
        __syncthreads();
    }
    for (int off = 32; off > 0; off >>= 1) {
#pragma unroll
        for (int e = 0; e < NEXP; e++) acc[e] += __shfl_xor(acc[e], off, 64);
    }

    float p[NEXP], s = 0.f;
#pragma unroll
    for (int e = 0; e < NEXP; e++) {
        p[e] = 1.f / (1.f + expf(-(acc[e] + gate_b[e])));
        s += p[e];
    }
    const float inv = 1.f / s;

    __shared__ float ps[4][NEXP];
    if (lane == 0) {
#pragma unroll
        for (int e = 0; e < NEXP; e++) ps[wave][e] = p[e] * inv;
        // top-3, strict > picks lowest index on ties (lax.top_k rule)
        int idx[TOPK]; float w[TOPK]; bool used[NEXP] = {};
        for (int k = 0; k < TOPK; k++) {
            float best = -1e30f; int bi = 0;
            for (int e = 0; e < NEXP; e++) {
                if (!used[e]) {
                    float sc = p[e] + route_bias[e];
                    if (sc > best) { best = sc; bi = e; }
                }
            }
            used[bi] = true; idx[k] = bi; w[k] = p[bi];
        }
        float wsum = w[0] + w[1] + w[2];
        for (int k = 0; k < TOPK; k++) {
            top_idx[n * TOPK + k] = idx[k];
            top_w[n * TOPK + k]   = w[k] / wsum;
        }
    }
    __syncthreads();
    if (threadIdx.x < NEXP) {
        int e = threadIdx.x;
        psum_part[(size_t)blockIdx.x * NEXP + e] =
            ps[0][e] + ps[1][e] + ps[2][e] + ps[3][e];
    }
}

// -------------------------- plan: counts, aux loss, padded offsets, tile table
__global__ __launch_bounds__(256) void plan_kernel(
    const int* __restrict__ top_idx, const float* __restrict__ psum_part,
    int* __restrict__ poff, int* __restrict__ cursor, int* __restrict__ tile_e,
    int* __restrict__ Ptot, float* __restrict__ out_aux)
{
    __shared__ int   cnt[NEXP];
    __shared__ float psum[NEXP];
    const int t = threadIdx.x;
    if (t < NEXP) { cnt[t] = 0; psum[t] = 0.f; }
    __syncthreads();

    for (int i = t; i < N_TOK * TOPK; i += 256)
        atomicAdd(&cnt[top_idx[i]], 1);

    float loc[NEXP];
#pragma unroll
    for (int e = 0; e < NEXP; e++) loc[e] = 0.f;
    for (int b = t; b < N_TOK / 4; b += 256) {
        const float* row = psum_part + (size_t)b * NEXP;
#pragma unroll
        for (int e = 0; e < NEXP; e++) loc[e] += row[e];
    }
#pragma unroll
    for (int e = 0; e < NEXP; e++) atomicAdd(&psum[e], loc[e]);
    __syncthreads();

    if (t == 0) {
        int off = 0, nt = 0; float aux = 0.f;
        for (int e = 0; e < NEXP; e++) {
            poff[e] = off; cursor[e] = 0;
            float P = psum[e] / (float)N_TOK;
            float F = (float)NEXP * (float)cnt[e] / ((float)TOPK * (float)N_TOK);
            aux += P * F;
            int tiles = (cnt[e] + 127) >> 7;
            for (int i = 0; i < tiles; i++) tile_e[nt++] = e;
            off += tiles << 7;                 // 128-aligned padded offsets
        }
        poff[NEXP] = off;
        *Ptot = off;
        for (int i = 0; i < N_TOK / 128; i++) tile_e[nt++] = NEXP;  // shared tiles
        while (nt < MAXTILE) tile_e[nt++] = -1;
        *out_aux = aux;
    }
}

// ----------------------------------------------------------- scatter to groups
__global__ __launch_bounds__(256) void scatter_kernel(
    const int* __restrict__ top_idx, const int* __restrict__ poff,
    int* __restrict__ cursor, int* __restrict__ tok_of_slot,
    int* __restrict__ slot_of_tok)
{
    int n = blockIdx.x * 256 + threadIdx.x;
    for (int k = 0; k < TOPK; k++) {
        int e = top_idx[n * TOPK + k];
        int pos = atomicAdd(&cursor[e], 1);
        int slot = poff[e] + pos;
        tok_of_slot[slot] = n;
        slot_of_tok[n * 4 + k] = slot;
    }
}

// --------------------------------------------- shared-expert slots (identity)
__global__ __launch_bounds__(256) void fillshared_kernel(
    const int* __restrict__ Ptot, int* __restrict__ tok_of_slot,
    int* __restrict__ slot_of_tok)
{
    int n = blockIdx.x * 256 + threadIdx.x;
    int P = *Ptot;
    tok_of_slot[P + n] = n;
    slot_of_tok[n * 4 + 3] = P + n;
}

// -------------------------------------------------------- x fp32 -> bf16 (+zero row)
__global__ __launch_bounds__(256) void xcvt_kernel(
    const float* __restrict__ x, short* __restrict__ xb)
{
    size_t i = (size_t)blockIdx.x * 256 + threadIdx.x;
    float4 v = ((const float4*)x)[i];
    short4 o;
    o.x = f2bf(v.x); o.y = f2bf(v.y); o.z = f2bf(v.z); o.w = f2bf(v.w);
    ((short4*)xb)[i] = o;
    if (blockIdx.x == 0) {
        short4 z; z.x = 0; z.y = 0; z.z = 0; z.w = 0;
        ((short4*)(xb + (size_t)N_TOK * DDIM))[threadIdx.x] = z;
    }
}

// ------------------------------------ transpose+convert: src[R][C] f32 -> dst[C][R] bf16
__global__ __launch_bounds__(256) void tcvt_kernel(
    const float* __restrict__ src, short* __restrict__ dst, int R, int C)
{
    __shared__ short tile[64][66];
    const float* s = src + (size_t)blockIdx.z * R * C;
    short* d = dst + (size_t)blockIdx.z * R * C;
    const int c0 = blockIdx.x * 64, r0 = blockIdx.y * 64;
    const int tc = threadIdx.x & 63, tq = threadIdx.x >> 6;

    for (int i = 0; i < 64; i += 4) {
        int r = i + tq;
        tile[tc][r] = f2bf(s[(size_t)(r0 + r) * C + c0 + tc]);
    }
    __syncthreads();
    for (int j = 0; j < 64; j += 4) {
        int c = j + tq;
        d[(size_t)(c0 + c) * R + r0 + tc] = tile[c][tc];
    }
}

// --------------------------------------------------------- bias concat (24 experts)
__global__ __launch_bounds__(256) void biascat_kernel(
    const float* __restrict__ b1, const float* __restrict__ sb1,
    const float* __restrict__ b2, const float* __restrict__ sb2,
    float* __restrict__ bias1_all, float* __restrict__ bias2_all)
{
    int i = blockIdx.x * 256 + threadIdx.x;
    if (i < 24 * HDIM) {
        bias1_all[i] = (i < NEXP * HDIM) ? b1[i] : sb1[i - NEXP * HDIM];
    } else {
        int j = i - 24 * HDIM;
        bias2_all[j] = (j < NEXP * DDIM) ? b2[j] : sb2[j - NEXP * DDIM];
    }
}

// --------------------------------------------------------------- unified GEMM
// 128x128 tile, BK=32, 4 waves, 4x4 16x16x32 bf16 MFMA frags; uniform tiles via
// tile_e[]; pad rows gather the zero row; epilogues are branchless bf16 stores.
template <bool FFN1>
__global__ __launch_bounds__(256) void gemm_kernel(
    const short* __restrict__ Abase, const int* __restrict__ tok_of_slot,
    const int* __restrict__ tile_e, const short* __restrict__ Wall,
    const float* __restrict__ bias_all, const short* __restrict__ zrow,
    short* __restrict__ outb)
{
    constexpr int KD = FFN1 ? DDIM : HDIM;
    constexpr int NC = FFN1 ? HDIM : DDIM;

    const int tile = blockIdx.y;
    const int e = tile_e[tile];
    if (e < 0) return;
    const int slot0 = tile * 128;
    const int n0 = blockIdx.x * 128;

    __shared__ short As[128 * 32];
    __shared__ short Bs[128 * 32];

    const int t = threadIdx.x;
    const int w = t >> 6, l = t & 63;
    const int quad = l >> 4, l16 = l & 15;
    const int wr = w >> 1, wc = w & 1;

    const int ra0 = w * 32 + (l >> 2);
    const int ra1 = ra0 + 16;
    const int ko  = (l & 3) << 3;

    const short *ap0, *ap1;
    if constexpr (FFN1) {
        int t0 = tok_of_slot[slot0 + ra0];
        int t1 = tok_of_slot[slot0 + ra1];
        ap0 = (t0 >= 0) ? Abase + (size_t)t0 * KD : zrow;
        ap1 = (t1 >= 0) ? Abase + (size_t)t1 * KD : zrow;
    } else {
        ap0 = Abase + (size_t)(slot0 + ra0) * KD;
        ap1 = Abase + (size_t)(slot0 + ra1) * KD;
    }
    ap0 += ko; ap1 += ko;
    const short* bbase = Wall + (size_t)e * NC * KD + (size_t)n0 * KD;
    const short* bp0 = bbase + (size_t)ra0 * KD + ko;
    const short* bp1 = bbase + (size_t)ra1 * KD + ko;

    short* asd0 = As + (w * 32) * 32;
    short* asd1 = As + (w * 32 + 16) * 32;
    short* bsd0 = Bs + (w * 32) * 32;
    short* bsd1 = Bs + (w * 32 + 16) * 32;

    floatx4 acc[4][4] = {};

    for (int k0 = 0; k0 < KD; k0 += 32) {
        gl_lds16(ap0, asd0); gl_lds16(ap1, asd1);
        gl_lds16(bp0, bsd0); gl_lds16(bp1, bsd1);
        ap0 += 32; ap1 += 32; bp0 += 32; bp1 += 32;
        __syncthreads();

        short8 af[4], bf[4];
#pragma unroll
        for (int i = 0; i < 4; i++)
            af[i] = *(const short8*)&As[(wr * 64 + i * 16 + l16) * 32 + quad * 8];
#pragma unroll
        for (int j = 0; j < 4; j++)
            bf[j] = *(const short8*)&Bs[(wc * 64 + j * 16 + l16) * 32 + quad * 8];
#pragma unroll
        for (int i = 0; i < 4; i++)
#pragma unroll
            for (int j = 0; j < 4; j++)
                acc[i][j] = __builtin_amdgcn_mfma_f32_16x16x32_bf16(af[i], bf[j], acc[i][j], 0, 0, 0);
        __syncthreads();
    }

    const int bias_off = e * NC;
#pragma unroll
    for (int j = 0; j < 4; j++) {
        const int col = n0 + wc * 64 + j * 16 + l16;
        const float bv = bias_all[bias_off + col];
#pragma unroll
        for (int i = 0; i < 4; i++)
#pragma unroll
            for (int r = 0; r < 4; r++) {
                const int row = slot0 + wr * 64 + i * 16 + quad * 4 + r;
                float v = acc[i][j][r] + bv;
                outb[(size_t)row * NC + col] = f2bf(FFN1 ? gelu_erf(v) : v);
            }
    }
}

// ------------------------------------------- combine: out[n] = y_shared + sum w_k y_k
__global__ __launch_bounds__(256) void combine_kernel(
    const short* __restrict__ ybuf, const int* __restrict__ slot_of_tok,
    const float* __restrict__ top_w, float* __restrict__ out)
{
    const int n = blockIdx.x;
    const int c = threadIdx.x;            // 256 threads x 4 cols
    const int s0 = slot_of_tok[n * 4 + 0];
    const int s1 = slot_of_tok[n * 4 + 1];
    const int s2 = slot_of_tok[n * 4 + 2];
    const int ss = slot_of_tok[n * 4 + 3];
    const float w0 = top_w[n * 3 + 0];
    const float w1 = top_w[n * 3 + 1];
    const float w2 = top_w[n * 3 + 2];

    short4 y0 = ((const short4*)(ybuf + (size_t)s0 * DDIM))[c];
    short4 y1 = ((const short4*)(ybuf + (size_t)s1 * DDIM))[c];
    short4 y2 = ((const short4*)(ybuf + (size_t)s2 * DDIM))[c];
    short4 ys = ((const short4*)(ybuf + (size_t)ss * DDIM))[c];

    float4 o;
    o.x = bf2f(ys.x) + w0 * bf2f(y0.x) + w1 * bf2f(y1.x) + w2 * bf2f(y2.x);
    o.y = bf2f(ys.y) + w0 * bf2f(y0.y) + w1 * bf2f(y1.y) + w2 * bf2f(y2.y);
    o.z = bf2f(ys.z) + w0 * bf2f(y0.z) + w1 * bf2f(y1.z) + w2 * bf2f(y2.z);
    o.w = bf2f(ys.w) + w0 * bf2f(y0.w) + w1 * bf2f(y1.w) + w2 * bf2f(y2.w);
    ((float4*)(out + (size_t)n * DDIM))[c] = o;
}

// ---------------------------------------------------------------------- launch
extern "C" void kernel_launch(void* const* d_in, const int* in_sizes, int n_in,
                              void* d_out, int out_size, void* d_ws, size_t ws_size,
                              hipStream_t stream)
{
    const float* x          = (const float*)d_in[0];
    const float* gate_W     = (const float*)d_in[1];
    const float* gate_b     = (const float*)d_in[2];
    const float* route_bias = (const float*)d_in[3];
    const float* W1         = (const float*)d_in[4];
    const float* b1         = (const float*)d_in[5];
    const float* W2         = (const float*)d_in[6];
    const float* b2         = (const float*)d_in[7];
    const float* sW1        = (const float*)d_in[8];
    const float* sb1        = (const float*)d_in[9];
    const float* sW2        = (const float*)d_in[10];
    const float* sb2        = (const float*)d_in[11];
    float* out = (float*)d_out;

    uint8_t* ws = (uint8_t*)d_ws;
    int*   top_idx   = (int*)(ws);                    //      49152
    float* top_w     = (float*)(ws + 49152);          //      49152
    int*   poff      = (int*)(ws + 98304);            //        128
    int*   cursor    = (int*)(ws + 98432);            //        128
    int*   Ptot      = (int*)(ws + 98560);            //        128
    int*   tile_e    = (int*)(ws + 98688);            //        640
    float* psum_part = (float*)(ws + 99328);          //      94208
    int*   tok_slot  = (int*)(ws + 193536);           //      77824 (SLOTS)
    int*   slot_tok  = (int*)(ws + 271360);           //      65536 [N][4]
    float* bias1_all = (float*)(ws + 336896);         //      73728 [24][H]
    float* bias2_all = (float*)(ws + 410624);         //      98304 [24][D]
    short* xb        = (short*)(ws + 512000);         //    8390656 (4096 rows + zero row)
    short* W1T       = (short*)(ws + 8902656);        //   37748736 [24][H][D]
    short* W2T       = (short*)(ws + 46651392);       //   37748736 [24][D][H]
    short* hbuf      = (short*)(ws + 84400128);       //   29884416 [SLOTS][H]
    short* ybuf      = (short*)(ws + 512000);         //   39845888 [SLOTS][D] — ALIASES
                      // xb+W1T (dead after gemm1; gemm2/combine don't touch them)
    const short* zrow = xb + (size_t)N_TOK * DDIM;
    // high-water: 84400128 + 29884416 = ~114.3 MB

    hipMemsetAsync(tok_slot, 0xFF, SLOTS * sizeof(int), stream);   // all slots -> tok -1

    xcvt_kernel<<<N_TOK * DDIM / 4 / 256, 256, 0, stream>>>(x, xb);
    tcvt_kernel<<<dim3(HDIM / 64, DDIM / 64, NEXP), 256, 0, stream>>>(W1, W1T, DDIM, HDIM);
    tcvt_kernel<<<dim3(HDIM / 64, DDIM / 64, 1), 256, 0, stream>>>(
        sW1, W1T + (size_t)NEXP * DDIM * HDIM, DDIM, HDIM);
    tcvt_kernel<<<dim3(DDIM / 64, HDIM / 64, NEXP), 256, 0, stream>>>(W2, W2T, HDIM, DDIM);
    tcvt_kernel<<<dim3(DDIM / 64, HDIM / 64, 1), 256, 0, stream>>>(
        sW2, W2T + (size_t)NEXP * HDIM * DDIM, HDIM, DDIM);
    biascat_kernel<<<(24 * HDIM + 24 * DDIM) / 256, 256, 0, stream>>>(
        b1, sb1, b2, sb2, bias1_all, bias2_all);

    gate_kernel<<<N_TOK / 4, 256, 0, stream>>>(x, gate_W, gate_b, route_bias,
                                               top_idx, top_w, psum_part);
    plan_kernel<<<1, 256, 0, stream>>>(top_idx, psum_part, poff, cursor, tile_e,
                                       Ptot, out + (size_t)N_TOK * DDIM);
    scatter_kernel<<<N_TOK / 256, 256, 0, stream>>>(top_idx, poff, cursor,
                                                    tok_slot, slot_tok);
    fillshared_kernel<<<N_TOK / 256, 256, 0, stream>>>(Ptot, tok_slot, slot_tok);

    gemm_kernel<true><<<dim3(HDIM / 128, MAXTILE), 256, 0, stream>>>(
        xb, tok_slot, tile_e, W1T, bias1_all, zrow, hbuf);
    gemm_kernel<false><<<dim3(DDIM / 128, MAXTILE), 256, 0, stream>>>(
        hbuf, tok_slot, tile_e, W2T, bias2_all, zrow, ybuf);
    combine_kernel<<<N_TOK, 256, 0, stream>>>(ybuf, slot_tok, top_w, out);
}

// Round 4
// 492.581 us; speedup vs baseline: 1.3108x; 1.0213x over previous
//
#include <hip/hip_runtime.h>
#include <hip/hip_bf16.h>
#include <stdint.h>

#define N_TOK 4096
#define DDIM  1024
#define HDIM  768
#define NEXP  23
#define TOPK  3
#define MAXTILE 152            // <=119 routed tiles + 32 shared tiles
#define SLOTS   19456          // padded routed (<=15232) + 4096 shared

typedef float floatx4 __attribute__((ext_vector_type(4)));
typedef short short8  __attribute__((ext_vector_type(8)));

__device__ __forceinline__ short f2bf(float f) {
    __hip_bfloat16 h = __float2bfloat16(f);
    return *reinterpret_cast<short*>(&h);
}
__device__ __forceinline__ float bf2f(short s) {
    unsigned u = ((unsigned)(unsigned short)s) << 16;
    return __uint_as_float(u);
}
__device__ __forceinline__ float gelu_erf(float v) {
    return 0.5f * v * (1.0f + erff(v * 0.70710678118654752f));
}
// async global->LDS, 16B/lane; LDS dest wave-uniform base (HW adds lane*16)
__device__ __forceinline__ void gl_lds16(const short* g, short* l) {
    __builtin_amdgcn_global_load_lds(
        (const __attribute__((address_space(1))) void*)g,
        (__attribute__((address_space(3))) void*)l, 16, 0, 0);
}

// ---------------------------------------------------------------- gate + topk
__global__ __launch_bounds__(256) void gate_kernel(
    const float* __restrict__ x, const float* __restrict__ gate_W,
    const float* __restrict__ gate_b, const float* __restrict__ route_bias,
    int* __restrict__ top_idx, float* __restrict__ top_w,
    float* __restrict__ psum_part)
{
    const int wave = threadIdx.x >> 6, lane = threadIdx.x & 63;
    const int n = blockIdx.x * 4 + wave;

    __shared__ float gw[64][25];
    float acc[NEXP];
#pragma unroll
    for (int e = 0; e < NEXP; e++) acc[e] = 0.f;

    const float* xr = x + (size_t)n * DDIM;
    for (int c0 = 0; c0 < DDIM; c0 += 64) {
        for (int idx = threadIdx.x; idx < 64 * NEXP; idx += 256)
            gw[idx / NEXP][idx % NEXP] = gate_W[(size_t)c0 * NEXP + idx];
        __syncthreads();
        float xd = xr[c0 + lane];
#pragma unroll
        for (int e = 0; e < NEXP; e++) acc[e] += xd * gw[lane][e];
        __syncthreads();
    }
    for (int off = 32; off > 0; off >>= 1) {
#pragma unroll
        for (int e = 0; e < NEXP; e++) acc[e] += __shfl_xor(acc[e], off, 64);
    }

    float p[NEXP], s = 0.f;
#pragma unroll
    for (int e = 0; e < NEXP; e++) {
        p[e] = 1.f / (1.f + expf(-(acc[e] + gate_b[e])));
        s += p[e];
    }
    const float inv = 1.f / s;

    __shared__ float ps[4][NEXP];
    if (lane == 0) {
#pragma unroll
        for (int e = 0; e < NEXP; e++) ps[wave][e] = p[e] * inv;
        // top-3, strict > picks lowest index on ties (lax.top_k rule)
        int idx[TOPK]; float w[TOPK]; bool used[NEXP] = {};
        for (int k = 0; k < TOPK; k++) {
            float best = -1e30f; int bi = 0;
            for (int e = 0; e < NEXP; e++) {
                if (!used[e]) {
                    float sc = p[e] + route_bias[e];
                    if (sc > best) { best = sc; bi = e; }
                }
            }
            used[bi] = true; idx[k] = bi; w[k] = p[bi];
        }
        float wsum = w[0] + w[1] + w[2];
        for (int k = 0; k < TOPK; k++) {
            top_idx[n * TOPK + k] = idx[k];
            top_w[n * TOPK + k]   = w[k] / wsum;
        }
    }
    __syncthreads();
    if (threadIdx.x < NEXP) {
        int e = threadIdx.x;
        psum_part[(size_t)blockIdx.x * NEXP + e] =
            ps[0][e] + ps[1][e] + ps[2][e] + ps[3][e];
    }
}

// -------------------------- plan: counts, aux loss, padded offsets, tile table
__global__ __launch_bounds__(256) void plan_kernel(
    const int* __restrict__ top_idx, const float* __restrict__ psum_part,
    int* __restrict__ poff, int* __restrict__ cursor, int* __restrict__ tile_e,
    int* __restrict__ Ptot, float* __restrict__ out_aux)
{
    __shared__ int   cnt[NEXP];
    __shared__ float psum[NEXP];
    const int t = threadIdx.x;
    if (t < NEXP) { cnt[t] = 0; psum[t] = 0.f; }
    __syncthreads();

    for (int i = t; i < N_TOK * TOPK; i += 256)
        atomicAdd(&cnt[top_idx[i]], 1);

    float loc[NEXP];
#pragma unroll
    for (int e = 0; e < NEXP; e++) loc[e] = 0.f;
    for (int b = t; b < N_TOK / 4; b += 256) {
        const float* row = psum_part + (size_t)b * NEXP;
#pragma unroll
        for (int e = 0; e < NEXP; e++) loc[e] += row[e];
    }
#pragma unroll
    for (int e = 0; e < NEXP; e++) atomicAdd(&psum[e], loc[e]);
    __syncthreads();

    if (t == 0) {
        int off = 0, nt = 0; float aux = 0.f;
        for (int e = 0; e < NEXP; e++) {
            poff[e] = off; cursor[e] = 0;
            float P = psum[e] / (float)N_TOK;
            float F = (float)NEXP * (float)cnt[e] / ((float)TOPK * (float)N_TOK);
            aux += P * F;
            int tiles = (cnt[e] + 127) >> 7;
            for (int i = 0; i < tiles; i++) tile_e[nt++] = e;
            off += tiles << 7;                 // 128-aligned padded offsets
        }
        poff[NEXP] = off;
        *Ptot = off;
        for (int i = 0; i < N_TOK / 128; i++) tile_e[nt++] = NEXP;  // shared tiles
        while (nt < MAXTILE) tile_e[nt++] = -1;
        *out_aux = aux;
    }
}

// ------------------------------------- scatter to groups + shared-expert slots
__global__ __launch_bounds__(256) void scatter_kernel(
    const int* __restrict__ top_idx, const int* __restrict__ poff,
    int* __restrict__ cursor, int* __restrict__ tok_of_slot,
    int* __restrict__ slot_of_tok, const int* __restrict__ Ptot)
{
    int n = blockIdx.x * 256 + threadIdx.x;
    for (int k = 0; k < TOPK; k++) {
        int e = top_idx[n * TOPK + k];
        int pos = atomicAdd(&cursor[e], 1);
        int slot = poff[e] + pos;
        tok_of_slot[slot] = n;
        slot_of_tok[n * 4 + k] = slot;
    }
    int P = *Ptot;
    tok_of_slot[P + n] = n;        // shared expert: identity mapping
    slot_of_tok[n * 4 + 3] = P + n;
}

// ------------------- fused: x fp32->bf16, zero row, bias concat (24 experts)
__global__ __launch_bounds__(256) void prep_kernel(
    const float* __restrict__ x, short* __restrict__ xb,
    const float* __restrict__ b1, const float* __restrict__ sb1,
    const float* __restrict__ b2, const float* __restrict__ sb2,
    float* __restrict__ bias1_all, float* __restrict__ bias2_all)
{
    const int b = blockIdx.x;
    if (b < N_TOK) {                      // x: one float4 per thread
        size_t i = (size_t)b * 256 + threadIdx.x;
        float4 v = ((const float4*)x)[i];
        short4 o;
        o.x = f2bf(v.x); o.y = f2bf(v.y); o.z = f2bf(v.z); o.w = f2bf(v.w);
        ((short4*)xb)[i] = o;
    } else if (b == N_TOK) {              // zero row (1024 shorts)
        short4 z; z.x = 0; z.y = 0; z.z = 0; z.w = 0;
        ((short4*)(xb + (size_t)N_TOK * DDIM))[threadIdx.x] = z;
    } else {                              // bias concat
        int i = (b - N_TOK - 1) * 256 + threadIdx.x;
        if (i < 24 * HDIM) {
            bias1_all[i] = (i < NEXP * HDIM) ? b1[i] : sb1[i - NEXP * HDIM];
        } else {
            int j = i - 24 * HDIM;
            if (j < 24 * DDIM)
                bias2_all[j] = (j < NEXP * DDIM) ? b2[j] : sb2[j - NEXP * DDIM];
        }
    }
}

// --------- transpose+convert: src[R][C] f32 -> dst[C][R] bf16, z=expert (23=shared)
// fully vectorized: float4 reads, short8 writes, LDS round-trip.
__global__ __launch_bounds__(256) void tcvt_kernel(
    const float* __restrict__ src, const float* __restrict__ ssrc,
    short* __restrict__ dst, int R, int C)
{
    __shared__ short tile[64][72];        // [c][r], stride 72: aligned + low-conflict
    const int e = blockIdx.z;
    const float* s = (e < NEXP) ? src + (size_t)e * R * C : ssrc;
    short* d = dst + (size_t)e * R * C;
    const int c0 = blockIdx.x * 64, r0 = blockIdx.y * 64;
    const int t = threadIdx.x;

    const int rr = t >> 4, cc = (t & 15) << 2;      // 16 rows/pass, float4/thread
#pragma unroll
    for (int i = 0; i < 64; i += 16) {
        float4 v = *(const float4*)&s[(size_t)(r0 + i + rr) * C + c0 + cc];
        tile[cc + 0][i + rr] = f2bf(v.x);
        tile[cc + 1][i + rr] = f2bf(v.y);
        tile[cc + 2][i + rr] = f2bf(v.z);
        tile[cc + 3][i + rr] = f2bf(v.w);
    }
    __syncthreads();
    const int cc2 = t >> 3, rr2 = (t & 7) << 3;     // 32 c-rows/pass, short8/thread
#pragma unroll
    for (int j = 0; j < 64; j += 32) {
        *(short8*)&d[(size_t)(c0 + j + cc2) * R + r0 + rr2] =
            *(const short8*)&tile[j + cc2][rr2];
    }
}

// --------------------------------------------------------------- unified GEMM
// 128x128 tile, BK=32, 4 waves, 4x4 16x16x32 bf16 MFMA frags; uniform tiles via
// tile_e[]; pad rows gather the zero row; epilogues are branchless bf16 stores.
template <bool FFN1>
__global__ __launch_bounds__(256) void gemm_kernel(
    const short* __restrict__ Abase, const int* __restrict__ tok_of_slot,
    const int* __restrict__ tile_e, const short* __restrict__ Wall,
    const float* __restrict__ bias_all, const short* __restrict__ zrow,
    short* __restrict__ outb)
{
    constexpr int KD = FFN1 ? DDIM : HDIM;
    constexpr int NC = FFN1 ? HDIM : DDIM;

    const int tile = blockIdx.y;
    const int e = tile_e[tile];
    if (e < 0) return;
    const int slot0 = tile * 128;
    const int n0 = blockIdx.x * 128;

    __shared__ short As[128 * 32];
    __shared__ short Bs[128 * 32];

    const int t = threadIdx.x;
    const int w = t >> 6, l = t & 63;
    const int quad = l >> 4, l16 = l & 15;
    const int wr = w >> 1, wc = w & 1;

    const int ra0 = w * 32 + (l >> 2);
    const int ra1 = ra0 + 16;
    const int ko  = (l & 3) << 3;

    const short *ap0, *ap1;
    if constexpr (FFN1) {
        int t0 = tok_of_slot[slot0 + ra0];
        int t1 = tok_of_slot[slot0 + ra1];
        ap0 = (t0 >= 0) ? Abase + (size_t)t0 * KD : zrow;
        ap1 = (t1 >= 0) ? Abase + (size_t)t1 * KD : zrow;
    } else {
        ap0 = Abase + (size_t)(slot0 + ra0) * KD;
        ap1 = Abase + (size_t)(slot0 + ra1) * KD;
    }
    ap0 += ko; ap1 += ko;
    const short* bbase = Wall + (size_t)e * NC * KD + (size_t)n0 * KD;
    const short* bp0 = bbase + (size_t)ra0 * KD + ko;
    const short* bp1 = bbase + (size_t)ra1 * KD + ko;

    short* asd0 = As + (w * 32) * 32;
    short* asd1 = As + (w * 32 + 16) * 32;
    short* bsd0 = Bs + (w * 32) * 32;
    short* bsd1 = Bs + (w * 32 + 16) * 32;

    floatx4 acc[4][4] = {};

    for (int k0 = 0; k0 < KD; k0 += 32) {
        gl_lds16(ap0, asd0); gl_lds16(ap1, asd1);
        gl_lds16(bp0, bsd0); gl_lds16(bp1, bsd1);
        ap0 += 32; ap1 += 32; bp0 += 32; bp1 += 32;
        __syncthreads();

        short8 af[4], bf[4];
#pragma unroll
        for (int i = 0; i < 4; i++)
            af[i] = *(const short8*)&As[(wr * 64 + i * 16 + l16) * 32 + quad * 8];
#pragma unroll
        for (int j = 0; j < 4; j++)
            bf[j] = *(const short8*)&Bs[(wc * 64 + j * 16 + l16) * 32 + quad * 8];
#pragma unroll
        for (int i = 0; i < 4; i++)
#pragma unroll
            for (int j = 0; j < 4; j++)
                acc[i][j] = __builtin_amdgcn_mfma_f32_16x16x32_bf16(af[i], bf[j], acc[i][j], 0, 0, 0);
        __syncthreads();
    }

    const int bias_off = e * NC;
#pragma unroll
    for (int j = 0; j < 4; j++) {
        const int col = n0 + wc * 64 + j * 16 + l16;
        const float bv = bias_all[bias_off + col];
#pragma unroll
        for (int i = 0; i < 4; i++)
#pragma unroll
            for (int r = 0; r < 4; r++) {
                const int row = slot0 + wr * 64 + i * 16 + quad * 4 + r;
                float v = acc[i][j][r] + bv;
                outb[(size_t)row * NC + col] = f2bf(FFN1 ? gelu_erf(v) : v);
            }
    }
}

// ------------------------------------------- combine: out[n] = y_shared + sum w_k y_k
__global__ __launch_bounds__(256) void combine_kernel(
    const short* __restrict__ ybuf, const int* __restrict__ slot_of_tok,
    const float* __restrict__ top_w, float* __restrict__ out)
{
    const int n = blockIdx.x;
    const int c = threadIdx.x;            // 256 threads x 4 cols
    const int s0 = slot_of_tok[n * 4 + 0];
    const int s1 = slot_of_tok[n * 4 + 1];
    const int s2 = slot_of_tok[n * 4 + 2];
    const int ss = slot_of_tok[n * 4 + 3];
    const float w0 = top_w[n * 3 + 0];
    const float w1 = top_w[n * 3 + 1];
    const float w2 = top_w[n * 3 + 2];

    short4 y0 = ((const short4*)(ybuf + (size_t)s0 * DDIM))[c];
    short4 y1 = ((const short4*)(ybuf + (size_t)s1 * DDIM))[c];
    short4 y2 = ((const short4*)(ybuf + (size_t)s2 * DDIM))[c];
    short4 ys = ((const short4*)(ybuf + (size_t)ss * DDIM))[c];

    float4 o;
    o.x = bf2f(ys.x) + w0 * bf2f(y0.x) + w1 * bf2f(y1.x) + w2 * bf2f(y2.x);
    o.y = bf2f(ys.y) + w0 * bf2f(y0.y) + w1 * bf2f(y1.y) + w2 * bf2f(y2.y);
    o.z = bf2f(ys.z) + w0 * bf2f(y0.z) + w1 * bf2f(y1.z) + w2 * bf2f(y2.z);
    o.w = bf2f(ys.w) + w0 * bf2f(y0.w) + w1 * bf2f(y1.w) + w2 * bf2f(y2.w);
    ((float4*)(out + (size_t)n * DDIM))[c] = o;
}

// ---------------------------------------------------------------------- launch
extern "C" void kernel_launch(void* const* d_in, const int* in_sizes, int n_in,
                              void* d_out, int out_size, void* d_ws, size_t ws_size,
                              hipStream_t stream)
{
    const float* x          = (const float*)d_in[0];
    const float* gate_W     = (const float*)d_in[1];
    const float* gate_b     = (const float*)d_in[2];
    const float* route_bias = (const float*)d_in[3];
    const float* W1         = (const float*)d_in[4];
    const float* b1         = (const float*)d_in[5];
    const float* W2         = (const float*)d_in[6];
    const float* b2         = (const float*)d_in[7];
    const float* sW1        = (const float*)d_in[8];
    const float* sb1        = (const float*)d_in[9];
    const float* sW2        = (const float*)d_in[10];
    const float* sb2        = (const float*)d_in[11];
    float* out = (float*)d_out;

    uint8_t* ws = (uint8_t*)d_ws;
    int*   top_idx   = (int*)(ws);                    //      49152
    float* top_w     = (float*)(ws + 49152);          //      49152
    int*   poff      = (int*)(ws + 98304);            //        128
    int*   cursor    = (int*)(ws + 98432);            //        128
    int*   Ptot      = (int*)(ws + 98560);            //        128
    int*   tile_e    = (int*)(ws + 98688);            //        640
    float* psum_part = (float*)(ws + 99328);          //      94208
    int*   tok_slot  = (int*)(ws + 193536);           //      77824 (SLOTS)
    int*   slot_tok  = (int*)(ws + 271360);           //      65536 [N][4]
    float* bias1_all = (float*)(ws + 336896);         //      73728 [24][H]
    float* bias2_all = (float*)(ws + 410624);         //      98304 [24][D]
    short* xb        = (short*)(ws + 512000);         //    8390656 (4096 rows + zero row)
    short* W1T       = (short*)(ws + 8902656);        //   37748736 [24][H][D]
    short* W2T       = (short*)(ws + 46651392);       //   37748736 [24][D][H]
    short* hbuf      = (short*)(ws + 84400128);       //   29884416 [SLOTS][H]
    short* ybuf      = (short*)(ws + 512000);         //   39845888 [SLOTS][D] — ALIASES
                      // xb+W1T (dead after gemm1; gemm2/combine don't touch them)
    const short* zrow = xb + (size_t)N_TOK * DDIM;
    // high-water: ~114.3 MB

    hipMemsetAsync(tok_slot, 0xFF, SLOTS * sizeof(int), stream);   // pad slots -> tok -1

    prep_kernel<<<N_TOK + 1 + (24 * (HDIM + DDIM) + 255) / 256, 256, 0, stream>>>(
        x, xb, b1, sb1, b2, sb2, bias1_all, bias2_all);
    tcvt_kernel<<<dim3(HDIM / 64, DDIM / 64, 24), 256, 0, stream>>>(
        W1, sW1, W1T, DDIM, HDIM);
    tcvt_kernel<<<dim3(DDIM / 64, HDIM / 64, 24), 256, 0, stream>>>(
        W2, sW2, W2T, HDIM, DDIM);

    gate_kernel<<<N_TOK / 4, 256, 0, stream>>>(x, gate_W, gate_b, route_bias,
                                               top_idx, top_w, psum_part);
    plan_kernel<<<1, 256, 0, stream>>>(top_idx, psum_part, poff, cursor, tile_e,
                                       Ptot, out + (size_t)N_TOK * DDIM);
    scatter_kernel<<<N_TOK / 256, 256, 0, stream>>>(top_idx, poff, cursor,
                                                    tok_slot, slot_tok, Ptot);

    gemm_kernel<true><<<dim3(HDIM / 128, MAXTILE), 256, 0, stream>>>(
        xb, tok_slot, tile_e, W1T, bias1_all, zrow, hbuf);
    gemm_kernel<false><<<dim3(DDIM / 128, MAXTILE), 256, 0, stream>>>(
        hbuf, tok_slot, tile_e, W2T, bias2_all, zrow, ybuf);
    combine_kernel<<<N_TOK, 256, 0, stream>>>(ybuf, slot_tok, top_w, out);
}

// Round 5
// 483.498 us; speedup vs baseline: 1.3354x; 1.0188x over previous
//
#include <hip/hip_runtime.h>
#include <hip/hip_bf16.h>
#include <stdint.h>

#define N_TOK 4096
#define DDIM  1024
#define HDIM  768
#define NEXP  23
#define TOPK  3
#define MAXTILE 152            // <=119 routed tiles + 32 shared tiles
#define SLOTS   19456

typedef float floatx4 __attribute__((ext_vector_type(4)));
typedef short short8  __attribute__((ext_vector_type(8)));

__device__ __forceinline__ short f2bf(float f) {
    __hip_bfloat16 h = __float2bfloat16(f);
    return *reinterpret_cast<short*>(&h);
}
__device__ __forceinline__ float bf2f(short s) {
    unsigned u = ((unsigned)(unsigned short)s) << 16;
    return __uint_as_float(u);
}
__device__ __forceinline__ float gelu_erf(float v) {
    return 0.5f * v * (1.0f + erff(v * 0.70710678118654752f));
}
// async global->LDS, 16B/lane; LDS dest wave-uniform base (HW adds lane*16)
__device__ __forceinline__ void gl_lds16(const short* g, short* l) {
    __builtin_amdgcn_global_load_lds(
        (const __attribute__((address_space(1))) void*)g,
        (__attribute__((address_space(3))) void*)l, 16, 0, 0);
}

// ------------------- fused: gate+topk | x fp32->bf16 | bias concat
__global__ __launch_bounds__(256) void prep_gate_kernel(
    const float* __restrict__ x, const float* __restrict__ gate_W,
    const float* __restrict__ gate_b, const float* __restrict__ route_bias,
    int* __restrict__ top_idx, float* __restrict__ top_w,
    float* __restrict__ psum_part, short* __restrict__ xb,
    const float* __restrict__ b1, const float* __restrict__ sb1,
    const float* __restrict__ b2, const float* __restrict__ sb2,
    float* __restrict__ bias1_all, float* __restrict__ bias2_all)
{
    const int b = blockIdx.x;
    if (b >= 1024) {
        const int bb = b - 1024;
        if (bb < N_TOK) {                 // x convert: one float4/thread
            size_t i = (size_t)bb * 256 + threadIdx.x;
            float4 v = ((const float4*)x)[i];
            short4 o;
            o.x = f2bf(v.x); o.y = f2bf(v.y); o.z = f2bf(v.z); o.w = f2bf(v.w);
            ((short4*)xb)[i] = o;
        } else {                          // bias concat
            int i = (bb - N_TOK) * 256 + threadIdx.x;
            if (i < 24 * HDIM) {
                bias1_all[i] = (i < NEXP * HDIM) ? b1[i] : sb1[i - NEXP * HDIM];
            } else {
                int j = i - 24 * HDIM;
                if (j < 24 * DDIM)
                    bias2_all[j] = (j < NEXP * DDIM) ? b2[j] : sb2[j - NEXP * DDIM];
            }
        }
        return;
    }
    // ---- gate: one wave per token, fp32-exact
    const int wave = threadIdx.x >> 6, lane = threadIdx.x & 63;
    const int n = b * 4 + wave;

    __shared__ float gw[64][25];
    float acc[NEXP];
#pragma unroll
    for (int e = 0; e < NEXP; e++) acc[e] = 0.f;

    const float* xr = x + (size_t)n * DDIM;
    for (int c0 = 0; c0 < DDIM; c0 += 64) {
        for (int idx = threadIdx.x; idx < 64 * NEXP; idx += 256)
            gw[idx / NEXP][idx % NEXP] = gate_W[(size_t)c0 * NEXP + idx];
        __syncthreads();
        float xd = xr[c0 + lane];
#pragma unroll
        for (int e = 0; e < NEXP; e++) acc[e] += xd * gw[lane][e];
        __syncthreads();
    }
    for (int off = 32; off > 0; off >>= 1) {
#pragma unroll
        for (int e = 0; e < NEXP; e++) acc[e] += __shfl_xor(acc[e], off, 64);
    }

    float p[NEXP], s = 0.f;
#pragma unroll
    for (int e = 0; e < NEXP; e++) {
        p[e] = 1.f / (1.f + expf(-(acc[e] + gate_b[e])));
        s += p[e];
    }
    const float inv = 1.f / s;

    __shared__ float ps[4][NEXP];
    if (lane == 0) {
#pragma unroll
        for (int e = 0; e < NEXP; e++) ps[wave][e] = p[e] * inv;
        // top-3, strict > picks lowest index on ties (lax.top_k rule)
        int idx[TOPK]; float w[TOPK]; bool used[NEXP] = {};
        for (int k = 0; k < TOPK; k++) {
            float best = -1e30f; int bi = 0;
            for (int e = 0; e < NEXP; e++) {
                if (!used[e]) {
                    float sc = p[e] + route_bias[e];
                    if (sc > best) { best = sc; bi = e; }
                }
            }
            used[bi] = true; idx[k] = bi; w[k] = p[bi];
        }
        float wsum = w[0] + w[1] + w[2];
        for (int k = 0; k < TOPK; k++) {
            top_idx[n * TOPK + k] = idx[k];
            top_w[n * TOPK + k]   = w[k] / wsum;
        }
    }
    __syncthreads();
    if (threadIdx.x < NEXP) {
        int e = threadIdx.x;
        psum_part[(size_t)b * NEXP + e] =
            ps[0][e] + ps[1][e] + ps[2][e] + ps[3][e];
    }
}

// -------------------------- plan: counts, aux loss, padded offsets, tile table
__global__ __launch_bounds__(256) void plan_kernel(
    const int* __restrict__ top_idx, const float* __restrict__ psum_part,
    int* __restrict__ poff, int* __restrict__ cursor, int* __restrict__ tile_e,
    int* __restrict__ Ptot, float* __restrict__ out_aux)
{
    __shared__ int   cnt[NEXP];
    __shared__ float psum[NEXP];
    __shared__ int   tbase[NEXP + 1];
    const int t = threadIdx.x;
    if (t < NEXP) { cnt[t] = 0; psum[t] = 0.f; }
    __syncthreads();

    for (int i = t; i < N_TOK * TOPK; i += 256)
        atomicAdd(&cnt[top_idx[i]], 1);

    float loc[NEXP];
#pragma unroll
    for (int e = 0; e < NEXP; e++) loc[e] = 0.f;
    for (int b = t; b < N_TOK / 4; b += 256) {
        const float* row = psum_part + (size_t)b * NEXP;
#pragma unroll
        for (int e = 0; e < NEXP; e++) loc[e] += row[e];
    }
#pragma unroll
    for (int e = 0; e < NEXP; e++) atomicAdd(&psum[e], loc[e]);
    __syncthreads();

    if (t == 0) {
        int tb = 0; float aux = 0.f;
        for (int e = 0; e < NEXP; e++) {
            tbase[e] = tb;
            float P = psum[e] / (float)N_TOK;
            float F = (float)NEXP * (float)cnt[e] / ((float)TOPK * (float)N_TOK);
            aux += P * F;
            tb += (cnt[e] + 127) >> 7;
        }
        tbase[NEXP] = tb;
        *Ptot = tb << 7;
        *out_aux = aux;
    }
    __syncthreads();
    const int tr = tbase[NEXP];
    if (t < NEXP) { poff[t] = tbase[t] << 7; cursor[t] = 0; }
    for (int i = t; i < MAXTILE; i += 256) {
        int v = -1;
        if (i < tr) {
            for (int e = 0; e < NEXP; e++)
                if (i >= tbase[e] && i < tbase[e + 1]) v = e;
        } else if (i < tr + N_TOK / 128) v = NEXP;
        tile_e[i] = v;
    }
}

// ------------------------------------- scatter to groups + shared-expert slots
__global__ __launch_bounds__(256) void scatter_kernel(
    const int* __restrict__ top_idx, const int* __restrict__ poff,
    int* __restrict__ cursor, int* __restrict__ tok_of_slot,
    int* __restrict__ slot_of_tok, const int* __restrict__ Ptot)
{
    int n = blockIdx.x * 256 + threadIdx.x;
    for (int k = 0; k < TOPK; k++) {
        int e = top_idx[n * TOPK + k];
        int pos = atomicAdd(&cursor[e], 1);
        int slot = poff[e] + pos;
        tok_of_slot[slot] = n;
        slot_of_tok[n * 4 + k] = slot;
    }
    int P = *Ptot;
    tok_of_slot[P + n] = n;        // shared expert: identity mapping
    slot_of_tok[n * 4 + 3] = P + n;
}

// --------- transpose+convert both weight families: f32 [R][C] -> bf16 [C][R]
__global__ __launch_bounds__(256) void tcvt_kernel(
    const float* __restrict__ W1, const float* __restrict__ sW1, short* __restrict__ W1T,
    const float* __restrict__ W2, const float* __restrict__ sW2, short* __restrict__ W2T)
{
    __shared__ short tile[64][72];
    const int z = blockIdx.z;
    int R, C; const float* s; short* d;
    if (z < 24) {
        R = DDIM; C = HDIM;
        s = (z < NEXP) ? W1 + (size_t)z * DDIM * HDIM : sW1;
        d = W1T + (size_t)z * DDIM * HDIM;
    } else {
        const int e = z - 24;
        R = HDIM; C = DDIM;
        s = (e < NEXP) ? W2 + (size_t)e * HDIM * DDIM : sW2;
        d = W2T + (size_t)e * HDIM * DDIM;
    }
    const int c0 = blockIdx.x * 64, r0 = blockIdx.y * 64;
    if (c0 >= C || r0 >= R) return;
    const int t = threadIdx.x;

    const int rr = t >> 4, cc = (t & 15) << 2;
#pragma unroll
    for (int i = 0; i < 64; i += 16) {
        float4 v = *(const float4*)&s[(size_t)(r0 + i + rr) * C + c0 + cc];
        tile[cc + 0][i + rr] = f2bf(v.x);
        tile[cc + 1][i + rr] = f2bf(v.y);
        tile[cc + 2][i + rr] = f2bf(v.z);
        tile[cc + 3][i + rr] = f2bf(v.w);
    }
    __syncthreads();
    const int cc2 = t >> 3, rr2 = (t & 7) << 3;
#pragma unroll
    for (int j = 0; j < 64; j += 32) {
        *(short8*)&d[(size_t)(c0 + j + cc2) * R + r0 + rr2] =
            *(const short8*)&tile[j + cc2][rr2];
    }
}

// --------------------------------------------------------------- unified GEMM
// 128x128 tile, BK=32, 3-stage async pipeline: raw s_barrier + fine vmcnt so
// prefetched global_load_lds stay in flight across barriers (no vmcnt(0) drain).
template <bool FFN1>
__global__ __launch_bounds__(256) void gemm_kernel(
    const short* __restrict__ Abase, const int* __restrict__ tok_of_slot,
    const int* __restrict__ tile_e, const short* __restrict__ Wall,
    const float* __restrict__ bias_all, short* __restrict__ outb)
{
    constexpr int KD = FFN1 ? DDIM : HDIM;
    constexpr int NC = FFN1 ? HDIM : DDIM;
    constexpr int KI = KD / 32;

    const int tile = blockIdx.y;
    const int e = tile_e[tile];
    if (e < 0) return;
    const int slot0 = tile * 128;
    const int n0 = blockIdx.x * 128;

    __shared__ short As[3][128 * 32];
    __shared__ short Bs[3][128 * 32];

    const int t = threadIdx.x;
    const int w = t >> 6, l = t & 63;
    const int quad = l >> 4, l16 = l & 15;
    const int wr = w >> 1, wc = w & 1;

    const int ra0 = w * 32 + (l >> 2);
    const int ra1 = ra0 + 16;
    const int ko  = (l & 3) << 3;

    const short *ap0, *ap1;
    if constexpr (FFN1) {
        int t0 = tok_of_slot[slot0 + ra0];
        int t1 = tok_of_slot[slot0 + ra1];
        t0 = ((unsigned)t0 < (unsigned)N_TOK) ? t0 : 0;  // pad slots: any valid row
        t1 = ((unsigned)t1 < (unsigned)N_TOK) ? t1 : 0;
        ap0 = Abase + (size_t)t0 * KD + ko;
        ap1 = Abase + (size_t)t1 * KD + ko;
    } else {
        ap0 = Abase + (size_t)(slot0 + ra0) * KD + ko;
        ap1 = Abase + (size_t)(slot0 + ra1) * KD + ko;
    }
    const short* bbase = Wall + (size_t)e * NC * KD + (size_t)n0 * KD;
    const short* bp0 = bbase + (size_t)ra0 * KD + ko;
    const short* bp1 = bbase + (size_t)ra1 * KD + ko;

    const int ldo0 = (w * 32) * 32;
    const int ldo1 = (w * 32 + 16) * 32;

    floatx4 acc[4][4] = {};

    // prologue: 3 k-groups in flight (12 vmem instrs/wave)
#pragma unroll
    for (int p = 0; p < 3; p++) {
        gl_lds16(ap0, &As[p][ldo0]); gl_lds16(ap1, &As[p][ldo1]);
        gl_lds16(bp0, &Bs[p][ldo0]); gl_lds16(bp1, &Bs[p][ldo1]);
        ap0 += 32; ap1 += 32; bp0 += 32; bp1 += 32;
    }

#pragma unroll
    for (int k = 0; k < KI; k++) {
        // retire exactly the oldest group (4 instrs); keep the rest in flight
        if (k < KI - 2)       asm volatile("s_waitcnt vmcnt(8)" ::: "memory");
        else if (k == KI - 2) asm volatile("s_waitcnt vmcnt(4)" ::: "memory");
        else                  asm volatile("s_waitcnt vmcnt(0)" ::: "memory");
        asm volatile("s_barrier" ::: "memory");   // all waves' group-k data in LDS

        const int s = k % 3;
        short8 af[4], bf[4];
#pragma unroll
        for (int i = 0; i < 4; i++)
            af[i] = *(const short8*)&As[s][(wr * 64 + i * 16 + l16) * 32 + quad * 8];
#pragma unroll
        for (int j = 0; j < 4; j++)
            bf[j] = *(const short8*)&Bs[s][(wc * 64 + j * 16 + l16) * 32 + quad * 8];
#pragma unroll
        for (int i = 0; i < 4; i++)
#pragma unroll
            for (int j = 0; j < 4; j++)
                acc[i][j] = __builtin_amdgcn_mfma_f32_16x16x32_bf16(af[i], bf[j], acc[i][j], 0, 0, 0);

        asm volatile("s_waitcnt lgkmcnt(0)" ::: "memory");
        asm volatile("s_barrier" ::: "memory");   // all waves done reading slot s
        if (k + 3 < KI) {                          // refill slot s (= (k+3)%3)
            gl_lds16(ap0, &As[s][ldo0]); gl_lds16(ap1, &As[s][ldo1]);
            gl_lds16(bp0, &Bs[s][ldo0]); gl_lds16(bp1, &Bs[s][ldo1]);
            ap0 += 32; ap1 += 32; bp0 += 32; bp1 += 32;
        }
    }

    const int bias_off = e * NC;
#pragma unroll
    for (int j = 0; j < 4; j++) {
        const int col = n0 + wc * 64 + j * 16 + l16;
        const float bv = bias_all[bias_off + col];
#pragma unroll
        for (int i = 0; i < 4; i++)
#pragma unroll
            for (int r = 0; r < 4; r++) {
                const int row = slot0 + wr * 64 + i * 16 + quad * 4 + r;
                float v = acc[i][j][r] + bv;
                outb[(size_t)row * NC + col] = f2bf(FFN1 ? gelu_erf(v) : v);
            }
    }
}

// ------------------------------------------- combine: out[n] = y_shared + sum w_k y_k
__global__ __launch_bounds__(256) void combine_kernel(
    const short* __restrict__ ybuf, const int* __restrict__ slot_of_tok,
    const float* __restrict__ top_w, float* __restrict__ out)
{
    const int n = blockIdx.x;
    const int c = threadIdx.x;
    const int s0 = slot_of_tok[n * 4 + 0];
    const int s1 = slot_of_tok[n * 4 + 1];
    const int s2 = slot_of_tok[n * 4 + 2];
    const int ss = slot_of_tok[n * 4 + 3];
    const float w0 = top_w[n * 3 + 0];
    const float w1 = top_w[n * 3 + 1];
    const float w2 = top_w[n * 3 + 2];

    short4 y0 = ((const short4*)(ybuf + (size_t)s0 * DDIM))[c];
    short4 y1 = ((const short4*)(ybuf + (size_t)s1 * DDIM))[c];
    short4 y2 = ((const short4*)(ybuf + (size_t)s2 * DDIM))[c];
    short4 ys = ((const short4*)(ybuf + (size_t)ss * DDIM))[c];

    float4 o;
    o.x = bf2f(ys.x) + w0 * bf2f(y0.x) + w1 * bf2f(y1.x) + w2 * bf2f(y2.x);
    o.y = bf2f(ys.y) + w0 * bf2f(y0.y) + w1 * bf2f(y1.y) + w2 * bf2f(y2.y);
    o.z = bf2f(ys.z) + w0 * bf2f(y0.z) + w1 * bf2f(y1.z) + w2 * bf2f(y2.z);
    o.w = bf2f(ys.w) + w0 * bf2f(y0.w) + w1 * bf2f(y1.w) + w2 * bf2f(y2.w);
    ((float4*)(out + (size_t)n * DDIM))[c] = o;
}

// ---------------------------------------------------------------------- launch
extern "C" void kernel_launch(void* const* d_in, const int* in_sizes, int n_in,
                              void* d_out, int out_size, void* d_ws, size_t ws_size,
                              hipStream_t stream)
{
    const float* x          = (const float*)d_in[0];
    const float* gate_W     = (const float*)d_in[1];
    const float* gate_b     = (const float*)d_in[2];
    const float* route_bias = (const float*)d_in[3];
    const float* W1         = (const float*)d_in[4];
    const float* b1         = (const float*)d_in[5];
    const float* W2         = (const float*)d_in[6];
    const float* b2         = (const float*)d_in[7];
    const float* sW1        = (const float*)d_in[8];
    const float* sb1        = (const float*)d_in[9];
    const float* sW2        = (const float*)d_in[10];
    const float* sb2        = (const float*)d_in[11];
    float* out = (float*)d_out;

    uint8_t* ws = (uint8_t*)d_ws;
    int*   top_idx   = (int*)(ws);                    //      49152
    float* top_w     = (float*)(ws + 49152);          //      49152
    int*   poff      = (int*)(ws + 98304);            //        128
    int*   cursor    = (int*)(ws + 98432);            //        128
    int*   Ptot      = (int*)(ws + 98560);            //        128
    int*   tile_e    = (int*)(ws + 98688);            //        640
    float* psum_part = (float*)(ws + 99328);          //      94208
    int*   tok_slot  = (int*)(ws + 193536);           //      77824 (SLOTS)
    int*   slot_tok  = (int*)(ws + 271360);           //      65536 [N][4]
    float* bias1_all = (float*)(ws + 336896);         //      73728 [24][H]
    float* bias2_all = (float*)(ws + 410624);         //      98304 [24][D]
    short* xb        = (short*)(ws + 512000);         //    8388608 [N][D]
    short* W1T       = (short*)(ws + 8902656);        //   37748736 [24][H][D]
    short* W2T       = (short*)(ws + 46651392);       //   37748736 [24][D][H]
    short* hbuf      = (short*)(ws + 84400128);       //   29884416 [SLOTS][H]
    short* ybuf      = (short*)(ws + 512000);         //   39845888 [SLOTS][D] — aliases
                      // xb+W1T (both dead after gemm1; gemm2/combine don't touch them)

    prep_gate_kernel<<<1024 + N_TOK + (24 * (HDIM + DDIM)) / 256, 256, 0, stream>>>(
        x, gate_W, gate_b, route_bias, top_idx, top_w, psum_part,
        xb, b1, sb1, b2, sb2, bias1_all, bias2_all);
    tcvt_kernel<<<dim3(16, 16, 48), 256, 0, stream>>>(W1, sW1, W1T, W2, sW2, W2T);
    plan_kernel<<<1, 256, 0, stream>>>(top_idx, psum_part, poff, cursor, tile_e,
                                       Ptot, out + (size_t)N_TOK * DDIM);
    scatter_kernel<<<N_TOK / 256, 256, 0, stream>>>(top_idx, poff, cursor,
                                                    tok_slot, slot_tok, Ptot);

    gemm_kernel<true><<<dim3(HDIM / 128, MAXTILE), 256, 0, stream>>>(
        xb, tok_slot, tile_e, W1T, bias1_all, hbuf);
    gemm_kernel<false><<<dim3(DDIM / 128, MAXTILE), 256, 0, stream>>>(
        hbuf, tok_slot, tile_e, W2T, bias2_all, ybuf);
    combine_kernel<<<N_TOK, 256, 0, stream>>>(ybuf, slot_tok, top_w, out);
}